// Round 5
// baseline (345.546 us; speedup 1.0000x reference)
//
#include <hip/hip_runtime.h>
#include <hip/hip_cooperative_groups.h>

// SetNorm: B=64, N=2048, D=256 fp32.
// out[b,n,d] = n < len[b] ? ((x[b,n,d] - mean_b) / (sqrt(var_b) + eps)) * w[d] + bias[d] : 0
//
// R5: single cooperative kernel. 1024 blocks (16 per batch, 128 rows each),
// 4 blocks/CU co-resident. Phase 1: per-slice partial sum/sumsq -> distinct
// ws slots (no atomics, no ws zeroing needed). grid.sync(). Phase 2: per-block
// stats re-reduce (16 pairs, L2-hot) + normalize own slice (just-read -> L2/L3
// hot). Nontemporal stores for out. No early return before grid.sync().

namespace cg = cooperative_groups;

#define BB 64
#define NN 2048
#define DD 256
#define EPSV 1e-5f
#define BPB 16                      // blocks per batch
#define ROWS_PER_BLOCK (NN / BPB)   // 128
#define GRID_BLOCKS (BB * BPB)      // 1024 = 4 blocks/CU on 256 CUs

typedef float f32x4 __attribute__((ext_vector_type(4)));

__global__ __launch_bounds__(256, 4) void setnorm_fused(
    const float* __restrict__ x, const int* __restrict__ lengths,
    const float* __restrict__ weights, const float* __restrict__ biases,
    float* __restrict__ partials, float* __restrict__ out) {
  const int slice = blockIdx.x & (BPB - 1);
  const int b = blockIdx.x >> 4;   // BPB = 16
  const int len = lengths[b];
  const int rowBase = slice * ROWS_PER_BLOCK;

  // ---------- phase 1: partial sum/sumsq over valid part of my slice ----------
  float sum = 0.f, sumsq = 0.f;
  int validRows = len - rowBase;
  if (validRows > ROWS_PER_BLOCK) validRows = ROWS_PER_BLOCK;
  const f32x4* xs = (const f32x4*)(x + ((size_t)b * NN + (size_t)rowBase) * DD);
  if (validRows > 0) {
    const int n4 = validRows * (DD / 4); // <= 8192
    for (int i = threadIdx.x; i < n4; i += 512) {
      f32x4 v = xs[i];
      sum += v.x + v.y + v.z + v.w;
      sumsq += v.x * v.x + v.y * v.y + v.z * v.z + v.w * v.w;
      const int j = i + 256;
      if (j < n4) {
        f32x4 u = xs[j];
        sum += u.x + u.y + u.z + u.w;
        sumsq += u.x * u.x + u.y * u.y + u.z * u.z + u.w * u.w;
      }
    }
  }
  #pragma unroll
  for (int off = 32; off > 0; off >>= 1) {
    sum += __shfl_down(sum, off, 64);
    sumsq += __shfl_down(sumsq, off, 64);
  }
  __shared__ float ssum[4], ssq[4];
  const int wave = threadIdx.x >> 6;
  const int lane = threadIdx.x & 63;
  if (lane == 0) { ssum[wave] = sum; ssq[wave] = sumsq; }
  __syncthreads();
  if (threadIdx.x == 0) {
    float ts = 0.f, tq = 0.f;
    #pragma unroll
    for (int w = 0; w < 4; ++w) { ts += ssum[w]; tq += ssq[w]; }
    partials[(b * BPB + slice) * 2 + 0] = ts;
    partials[(b * BPB + slice) * 2 + 1] = tq;
  }

  cg::this_grid().sync();

  // ---------- phase 2: stats + normalize my slice ----------
  f32x4* op = ((f32x4*)out) + ((size_t)b * NN + (size_t)rowBase) * (DD / 4);

  if (rowBase >= len) {
    // fully-invalid slice: stream zeros, no stats needed
    const f32x4 z = {0.f, 0.f, 0.f, 0.f};
    #pragma unroll
    for (int i = 0; i < 32; ++i)
      __builtin_nontemporal_store(z, op + i * 256 + threadIdx.x);
    return;
  }

  __shared__ float s_mean, s_inv;
  if (threadIdx.x < 64) {
    float s = 0.f, q = 0.f;
    if (threadIdx.x < BPB) {
      s = partials[(b * BPB + threadIdx.x) * 2 + 0];
      q = partials[(b * BPB + threadIdx.x) * 2 + 1];
    }
    #pragma unroll
    for (int off = 8; off > 0; off >>= 1) {
      s += __shfl_down(s, off, 64);
      q += __shfl_down(q, off, 64);
    }
    if (threadIdx.x == 0) {
      const float denom = (float)len * (float)DD;
      const float mean = s / denom;
      float var = q / denom - mean * mean;
      var = fmaxf(var, 0.f);
      s_mean = mean;
      s_inv = 1.f / (sqrtf(var) + EPSV);
    }
  }
  __syncthreads();
  const float mean = s_mean;
  const float inv = s_inv;

  const int d4 = threadIdx.x & 63;
  const f32x4 w = ((const f32x4*)weights)[d4];
  const f32x4 bi = ((const f32x4*)biases)[d4];
  const int rowT = rowBase + (threadIdx.x >> 6); // row in iter 0; +4 per iter

  #pragma unroll 4
  for (int i = 0; i < 32; ++i) {
    const int o4 = i * 256 + threadIdx.x;
    const int row = rowT + i * 4;
    f32x4 o = {0.f, 0.f, 0.f, 0.f};
    if (row < len) {
      const f32x4 v = xs[o4];        // just read in phase 1 -> L2/L3 hot
      o.x = (v.x - mean) * inv * w.x + bi.x;
      o.y = (v.y - mean) * inv * w.y + bi.y;
      o.z = (v.z - mean) * inv * w.z + bi.z;
      o.w = (v.w - mean) * inv * w.w + bi.w;
    }
    __builtin_nontemporal_store(o, op + o4);
  }
}

extern "C" void kernel_launch(void* const* d_in, const int* in_sizes, int n_in,
                              void* d_out, int out_size, void* d_ws, size_t ws_size,
                              hipStream_t stream) {
  const float* x = (const float*)d_in[0];
  const int* lengths = (const int*)d_in[1];
  const float* weights = (const float*)d_in[2];
  const float* biases = (const float*)d_in[3];
  float* out = (float*)d_out;
  float* partials = (float*)d_ws; // BB*BPB*2 floats = 8 KB, all slots written

  void* args[] = {(void*)&x, (void*)&lengths, (void*)&weights,
                  (void*)&biases, (void*)&partials, (void*)&out};
  hipLaunchCooperativeKernel((void*)setnorm_fused, dim3(GRID_BLOCKS),
                             dim3(256), args, 0, stream);
}